// Round 5
// baseline (84.151 us; speedup 1.0000x reference)
//
#include <hip/hip_runtime.h>

// Problem constants
#define RES 128

typedef _Float16 half8 __attribute__((ext_vector_type(8)));
typedef float    f32x4 __attribute__((ext_vector_type(4)));

// ---------------------------------------------------------------------------
// Single fused kernel: grid 256 blocks x 512 thr (8 waves = 2 waves/SIMD,
// 1 block/CU). Block bid -> (b = bid>>5, mt = (bid>>3)&3, nt = bid&7):
// output tile M32 (m0=mt*32) x N16 (n0=nt*16) for batch b, FULL K=4096.
//
// Setup: all 4096 points' (tx,ty), grid-sampled c/128, and delta phasor
// e^{i*2pi*ty*16/128} staged in LDS (96 KB).
// K-loop: wave w owns points [w*512, w*512+512), 32 MFMA-steps of 16 points.
// Fragments are generated per-lane directly into registers (no LDS tiles,
// no barriers in the loop): A-frag lane l15 = m-row, q = k-quad (points
// p = w*512 + s*16 + 4q + j); frag for m+16 derived from frag m via the
// precomputed delta phasor (halves the A-side transcendentals).
// Complex mul via sign/shuffle on B: Re = a.(br,-bi), Im = a.(bi,br).
// Epilogue: 8-way cross-wave f32 sum via LDS, write f32 out directly.
// No workspace partials, no second kernel, no global sync.
// ---------------------------------------------------------------------------
__global__ __launch_bounds__(512, 2) void fused_kernel(const float* __restrict__ ksp,
                                                       const float* __restrict__ traj,
                                                       float2* __restrict__ out) {
    __shared__ float2 st[4096];   // (tx, ty)
    __shared__ float2 sc[4096];   // c[b,p]/128
    __shared__ float2 sd[4096];   // delta phasor e^{i*2pi*ty/8}
    __shared__ float  red[8192];  // 8 waves x 32m x 16n x (R,I)

    const int bid  = blockIdx.x;          // 0..255
    const int b    = bid >> 5;            // 0..7
    const int mt   = (bid >> 3) & 3;      // 0..3
    const int nt   = bid & 7;             // 0..7
    const int m0   = mt * 32, n0 = nt * 16;
    const int tid  = threadIdx.x;
    const int w    = tid >> 6;            // wave 0..7
    const int lane = tid & 63;
    const int l15  = lane & 15;
    const int q    = lane >> 4;

    // ---- setup: traj + bilinear grid-sample + delta phasor for ALL 4096 p ----
#pragma unroll
    for (int it = 0; it < 8; ++it) {
        const int p = it * 512 + tid;
        const float2 t2 = *(const float2*)(traj + 2 * p);
        st[p] = t2;
        const float x = t2.x + 63.5f, y = t2.y + 63.5f;
        const float x0f = floorf(x), y0f = floorf(y);
        const float wx = x - x0f, wy = y - y0f;
        const int ix0 = (int)x0f, iy0 = (int)y0f;
        float re = 0.f, im = 0.f;
#pragma unroll
        for (int dy = 0; dy < 2; ++dy)
#pragma unroll
            for (int dx = 0; dx < 2; ++dx) {
                const int ix = ix0 + dx, iy = iy0 + dy;
                const float wgt = (dx ? wx : 1.f - wx) * (dy ? wy : 1.f - wy);
                if (ix >= 0 && ix < RES && iy >= 0 && iy < RES) {
                    const float2 v = *(const float2*)(ksp + ((b * RES + iy) * RES + ix) * 2);
                    re = fmaf(v.x, wgt, re);
                    im = fmaf(v.y, wgt, im);
                }
            }
        sc[p] = make_float2(re * (1.f / 128.f), im * (1.f / 128.f));
        const float rd = t2.y * 0.125f;              // ty*16/128 revolutions
        const float fd = rd - floorf(rd);
        sd[p] = make_float2(__builtin_amdgcn_cosf(fd), __builtin_amdgcn_sinf(fd));
    }
    __syncthreads();

    f32x4 accR0 = {0.f, 0.f, 0.f, 0.f};
    f32x4 accI0 = {0.f, 0.f, 0.f, 0.f};
    f32x4 accR1 = {0.f, 0.f, 0.f, 0.f};
    f32x4 accI1 = {0.f, 0.f, 0.f, 0.f};

    const float inv = 1.f / 128.f;
    const float xm = ((float)(m0 + l15) - 64.f) * inv;
    const float xn = ((float)(n0 + l15) - 64.f) * inv;
    const half8 SGN = {(_Float16)1.f, (_Float16)-1.f, (_Float16)1.f, (_Float16)-1.f,
                       (_Float16)1.f, (_Float16)-1.f, (_Float16)1.f, (_Float16)-1.f};
    const int pw = w * 512 + q * 4;

    for (int s = 0; s < 32; ++s) {
        half8 av0, av1, bv;
#pragma unroll
        for (int j = 0; j < 4; ++j) {
            const int p = pw + s * 16 + j;
            const float2 t2 = st[p];   // LDS broadcast (4 addrs per wave)
            const float2 c2 = sc[p];
            const float2 d2 = sd[p];
            // B: plain Ax phasor at n = n0 + l15
            float rb = t2.x * xn;
            rb -= floorf(rb);
            bv[2 * j]     = (_Float16)__builtin_amdgcn_cosf(rb);
            bv[2 * j + 1] = (_Float16)__builtin_amdgcn_sinf(rb);
            // A (m = m0 + l15): c-folded Ay phasor
            float ra = t2.y * xm;
            ra -= floorf(ra);
            const float cs = __builtin_amdgcn_cosf(ra);
            const float sn = __builtin_amdgcn_sinf(ra);
            const float ar0 = c2.x * cs - c2.y * sn;
            const float ai0 = c2.x * sn + c2.y * cs;
            av0[2 * j]     = (_Float16)ar0;
            av0[2 * j + 1] = (_Float16)ai0;
            // A (m + 16) = A(m) * delta
            av1[2 * j]     = (_Float16)(ar0 * d2.x - ai0 * d2.y);
            av1[2 * j + 1] = (_Float16)(ar0 * d2.y + ai0 * d2.x);
        }
        const half8 b1 = bv * SGN;                                      // (br,-bi)
        const half8 b2 = __builtin_shufflevector(bv, bv,
                                                 1, 0, 3, 2, 5, 4, 7, 6); // (bi,br)
        accR0 = __builtin_amdgcn_mfma_f32_16x16x32_f16(av0, b1, accR0, 0, 0, 0);
        accI0 = __builtin_amdgcn_mfma_f32_16x16x32_f16(av0, b2, accI0, 0, 0, 0);
        accR1 = __builtin_amdgcn_mfma_f32_16x16x32_f16(av1, b1, accR1, 0, 0, 0);
        accI1 = __builtin_amdgcn_mfma_f32_16x16x32_f16(av1, b2, accI1, 0, 0, 0);
    }

    // ---- cross-wave reduction: C/D layout col=l15 (n), row=q*4+rg (m) ----
    float* rw = red + w * 1024;
#pragma unroll
    for (int rg = 0; rg < 4; ++rg) {
        const int r0 = ((q * 4 + rg) * 16 + l15) * 2;
        rw[r0]     = accR0[rg];
        rw[r0 + 1] = accI0[rg];
        const int r1 = ((16 + q * 4 + rg) * 16 + l15) * 2;
        rw[r1]     = accR1[rg];
        rw[r1 + 1] = accI1[rg];
    }
    __syncthreads();

    const int lm = tid >> 4;      // 0..31
    const int ln = tid & 15;      // 0..15
    const int ri = (lm * 16 + ln) * 2;
    float sr = 0.f, si = 0.f;
#pragma unroll
    for (int ww = 0; ww < 8; ++ww) {
        sr += red[ww * 1024 + ri];
        si += red[ww * 1024 + ri + 1];
    }
    out[(b * RES + m0 + lm) * RES + n0 + ln] = make_float2(sr, si);
}

// ---------------------------------------------------------------------------
extern "C" void kernel_launch(void* const* d_in, const int* in_sizes, int n_in,
                              void* d_out, int out_size, void* d_ws, size_t ws_size,
                              hipStream_t stream) {
    const float* ksp  = (const float*)d_in[0];   // (B,1,128,128,2) fp32
    const float* traj = (const float*)d_in[1];   // (4096,2) fp32

    hipLaunchKernelGGL(fused_kernel, dim3(256), dim3(512), 0, stream,
                       ksp, traj, (float2*)d_out);
}